// Round 9
// baseline (465.525 us; speedup 1.0000x reference)
//
#include <hip/hip_runtime.h>

// Problem constants
#define B_      64
#define CIN     32
#define H_      28
#define W_      28
#define OH_     24
#define OW_     24
#define COUT    128
#define NPOS    (OH_ * OW_)          // 576
#define HW_     (H_ * W_)            // 784
#define XSTRIDE (CIN * HW_)          // 25088 floats per image
#define PSTRIDE (CIN * HW_)          // f2 elements per image-pair block

// ---------------- Main path: 4 images/lane, 1 tree/block, rolled j3 ----------------
#define BLK      192
#define NQ       16                  // bq in [0,16): images bq,+16,+32,+48
#define NLANES   (NQ * NPOS)         // 9216
#define NCH      (NLANES / BLK)      // 48 chunks
#define NXCD     8
#define CPX      (NCH / NXCD)        // 6 chunks per XCD
// grid = NCH * COUT = 6144

// WS: XPAIR f2[32*PSTRIDE] | OFFS int[COUT*36*6] | COEF2 f4[COUT*43*32] (dup records)
#define XP_BYTES    (32 * PSTRIDE * 8)          // 6422528
#define OFF_BYTES   (COUT * 36 * 6 * 4)         // 110592
#define COEF2_BYTES (COUT * 43 * 32 * 16)       // 2818048
#define WS_NEW      (XP_BYTES + OFF_BYTES + COEF2_BYTES)   // ~9.35 MB

// ---------------- r6 fallback path constants (proven 374 us) ----------------
#define BLOCK    256
#define BHALF    32
#define NLANES6  (BHALF * NPOS)      // 18432
#define UBLOCKS6 (NLANES6 / BLOCK)   // 72
#define TPB6     2
#define NTP      64
#define TGROUPS6 (NTP / TPB6)        // 32
#define UPX6     (UBLOCKS6 / NXCD)   // 9
#define CF4_PER_TP (43 * 32)
#define OFF6_INTS  (NTP * 36 * 12)
#define WS_R6      ((OFF6_INTS + NTP * 43 * 128) * 4)    // 1519616

typedef float f2 __attribute__((ext_vector_type(2)));
typedef float f4 __attribute__((ext_vector_type(4)));
typedef __fp16 h2v __attribute__((ext_vector_type(2)));   // matches cvt_pkrtz return
struct p2 { f2 a, b; };   // two image-pair units per lane

__device__ __forceinline__ f2 pkfma(f2 x, f2 h, f2 l) {
    return __builtin_elementwise_fma(x, h, l);   // v_pk_fma_f32 (no asm: r5 lesson)
}

__device__ __forceinline__ f2 clamp2(f2 v) {
    f2 r;
    r.x = __builtin_amdgcn_fmed3f(v.x, 0.0f, 1.0f);
    r.y = __builtin_amdgcn_fmed3f(v.y, 0.0f, 1.0f);
    return r;
}

// DFS Horner contraction. Record a0 is an f4 whose {x,y} and {z,w} are the
// ALIGNED sub-pairs the leaf pkfma consumes directly (mov-free: r6-proven;
// r7's splat variant cost ~128 v_movs/node). Works for both layouts:
//   main path: {lo,lo,hi,hi} (f2 lanes = image pair)
//   r6 path:   {lo_t0,lo_t1,hi_t0,hi_t1} (f2 lanes = tree pair)
template<int M>
struct RecD {
    static __device__ __forceinline__ p2 go(const f4* __restrict__ C, int a0,
                                            const p2* xs) {
        p2 lo = RecD<M - 1>::go(C, a0, xs);
        p2 hi = RecD<M - 1>::go(C, a0 + (1 << (M - 2)), xs);
        p2 r;
        r.a = pkfma(xs[6 - M].a, hi.a, lo.a);
        r.b = pkfma(xs[6 - M].b, hi.b, lo.b);
        return r;
    }
};
template<>
struct RecD<1> {
    static __device__ __forceinline__ p2 go(const f4* __restrict__ C, int a0,
                                            const p2* xs) {
        f4 q = C[a0];                 // ds_read_b128, uniform addr -> broadcast
        f2 lo; lo.x = q.x; lo.y = q.y;
        f2 hi; hi.x = q.z; hi.y = q.w;
        p2 r;
        r.a = pkfma(xs[5].a, hi, lo);
        r.b = pkfma(xs[5].b, hi, lo);
        return r;
    }
};

__device__ __forceinline__ p2 contractD(const f4* __restrict__ C, const p2 xs[6]) {
    p2 r = RecD<6>::go(C, 0, xs);
    r.a = clamp2(r.a);
    r.b = clamp2(r.b);
    return r;
}

__device__ __forceinline__ unsigned pk16(f2 v) {
    h2v h = __builtin_amdgcn_cvt_pkrtz(v.x, v.y);   // v_cvt_pkrtz_f16_f32
    return __builtin_bit_cast(unsigned, h);
}
__device__ __forceinline__ f2 unpk16(unsigned u) {
    h2v h = __builtin_bit_cast(h2v, u);
    f2 r; r.x = (float)h.x; r.y = (float)h.y;
    return r;
}

// Main kernel: one tree per block; j3 loop ROLLED (I$ body ~14KB vs ~60KB
// unrolled — theory: the constant ~35% VALU-idle across r1..r7 is I-fetch).
__global__ __launch_bounds__(BLK, 4)
void lutconv_s(const char* __restrict__ xpc,
               const int* __restrict__ OFFS,
               const f4* __restrict__ COEF,
               float* __restrict__ out) {
    __shared__ f4 CLs[43 * 32];          // 22016 B coeff image (duplicated records)
    __shared__ uint2 H2s[6][BLK];        // 9216 B f16-packed h2 stash

    // XCD-locality decode: 6 consecutive chunks pinned per XCD; per-XCD L2
    // working set = 400KB x-slice + 2.8MB COEF < 4MB.
    const int bid = blockIdx.x;
    const int xcd = bid & 7;
    const int j   = bid >> 3;            // 0..767
    const int t   = j & 127;             // tree
    const int usl = j >> 7;              // 0..5
    const int us  = xcd * CPX + usl;     // chunk 0..47

    // Stage coefficients: 1376 f4.
    {
        const f4* src = COEF + (size_t)t * (43 * 32);
#pragma unroll
        for (int k = 0; k < 8; ++k) {
            int i = k * BLK + threadIdx.x;
            if (i < 43 * 32) CLs[i] = src[i];
        }
    }

    const int g   = us * BLK + threadIdx.x;    // 0..9215
    const int bq  = g / NPOS;                  // 0..15
    const int pos = g - bq * NPOS;
    const int oh  = pos / OW_;
    const int ow  = pos - oh * OW_;
    const unsigned lin   = oh * W_ + ow;
    const unsigned byteA = (bq * PSTRIDE + lin) * 8u;          // pair (bq, bq+32)
    const unsigned byteB = ((bq + 16) * PSTRIDE + lin) * 8u;   // pair (bq+16, bq+48)
    __syncthreads();

#pragma unroll 1
    for (int j3 = 0; j3 < 6; ++j3) {
        const int* oi3 = OFFS + t * 216 + j3 * 36;   // uniform -> s_load
        p2 h1[6];                                    // static index (j1 unrolled)
#pragma unroll
        for (int j1 = 0; j1 < 6; ++j1) {
            p2 xs[6];
#pragma unroll
            for (int jj = 0; jj < 6; ++jj) {
                int o = __builtin_amdgcn_readfirstlane(oi3[j1 * 6 + jj]);
                const char* p = xpc + o;             // scalar base
                p2 w;
                w.a = *(const f2*)(p + byteA);       // global_load_dwordx2 saddr
                w.b = *(const f2*)(p + byteB);
                xs[jj] = w;
            }
            h1[j1] = contractD(CLs + (j3 * 7 + j1) * 32, xs);
        }
        p2 h2 = contractD(CLs + (j3 * 7 + 6) * 32, h1);
        // f16 stash (rtz err <= 3e-3 into root; threshold 1.3e-2 @ bf16 compare)
        H2s[j3][threadIdx.x] = make_uint2(pk16(h2.a), pk16(h2.b));
    }

    // L3 root: read back 6 h2 values, contract.
    p2 xs[6];
#pragma unroll
    for (int j3 = 0; j3 < 6; ++j3) {
        uint2 v = H2s[j3][threadIdx.x];
        xs[j3].a = unpk16(v.x);
        xs[j3].b = unpk16(v.y);
    }
    p2 r = contractD(CLs + 42 * 32, xs);

    const size_t istr = (size_t)16 * COUT * NPOS;
    size_t o0 = ((size_t)bq * COUT + t) * NPOS + pos;
    out[o0]            = r.a.x;   // bq
    out[o0 + 2 * istr] = r.a.y;   // bq+32
    out[o0 + istr]     = r.b.x;   // bq+16
    out[o0 + 3 * istr] = r.b.y;   // bq+48
}

// Interleave image pairs (p, p+32) as f2.
__global__ void prep_xp(const float* __restrict__ x, f2* __restrict__ xp) {
    int i = blockIdx.x * 256 + threadIdx.x;
    if (i < 32 * PSTRIDE) {
        int p = i / PSTRIDE;
        int r = i - p * PSTRIDE;
        f2 v;
        v.x = x[p * XSTRIDE + r];
        v.y = x[(p + 32) * XSTRIDE + r];
        xp[i] = v;
    }
}

// Per (tree, node): resolve maps, Mobius-transform LUT (shfl_xor butterfly),
// write DUPLICATED records {lo,lo,hi,hi} + byte gather offsets (x8 for f2).
__global__ void prep_cf2(const int* __restrict__ map1, const float* __restrict__ lut1,
                         const int* __restrict__ map2, const float* __restrict__ lut2,
                         const int* __restrict__ map3, const float* __restrict__ lut3,
                         int* __restrict__ OFFS, float* __restrict__ COEF) {
    const int rec  = blockIdx.x % 43;
    const int t    = blockIdx.x / 43;
    const int lane = threadIdx.x;

    const float* lp;
    int node;
    if (rec == 42) {
        node = 42;
        lp = lut3 + t * 64;
    } else {
        const int j3 = rec / 7;
        const int jr = rec - 7 * j3;
        const int n2 = map3[t * 6 + j3];
        if (jr == 6) {
            node = j3 * 7 + 6;
            lp = lut2 + (t * 6 + n2) * 64;
        } else {
            const int n1 = map2[(t * 6 + n2) * 6 + jr];
            node = j3 * 7 + jr;
            lp = lut1 + (t * 36 + n1) * 64;
            if (lane < 6) {
                int m  = map1[(t * 36 + n1) * 6 + lane];
                int c  = m / 25;
                int r  = m - 25 * c;
                int kh = r / 5;
                int kw = r - 5 * kh;
                OFFS[t * 216 + (j3 * 6 + jr) * 6 + lane] =
                    (c * HW_ + kh * W_ + kw) * 8;   // byte offset into f2 block
            }
        }
    }

    float cv = lp[lane];
#pragma unroll
    for (int s = 1; s < 64; s <<= 1) {
        float o = __shfl_xor(cv, s);
        if (lane & s) cv -= o;
    }
    // Duplicated record: entry-pair a={lane>>1}, half h={lane&1} (0=lo,1=hi):
    // f4 = {lo,lo,hi,hi}.
    float* cp = COEF + ((size_t)t * 43 + node) * 128;
    int a = lane >> 1, h = lane & 1;
    cp[a * 4 + h * 2]     = cv;
    cp[a * 4 + h * 2 + 1] = cv;
}

// ======================= r6 fallback path (proven 374 us) =======================
__global__ __launch_bounds__(BLOCK, 3)
void lutconv_l(const float* __restrict__ x,
               const int* __restrict__ OFFS,
               const f4* __restrict__ COEF,
               float* __restrict__ out) {
    __shared__ f4 CLs[CF4_PER_TP];

    const int bid = blockIdx.x;
    const int xcd = bid % NXCD;
    const int j   = bid / NXCD;
    const int tg  = j % TGROUPS6;
    const int us  = j / TGROUPS6;
    const int u   = xcd * UPX6 + us;

    const int g   = u * BLOCK + threadIdx.x;
    const int b0  = g / NPOS;
    const int pos = g - b0 * NPOS;
    const int oh  = pos / OW_;
    const int ow  = pos - oh * OW_;
    const unsigned lin   = oh * W_ + ow;
    const unsigned voff0 = (b0 * XSTRIDE + lin) * 4u;
    const unsigned voff1 = voff0 + BHALF * XSTRIDE * 4u;
    const char* xc = (const char*)x;

#pragma unroll 1
    for (int tpi = 0; tpi < TPB6; ++tpi) {
        const int tp = tg * TPB6 + tpi;

        if (tpi) __syncthreads();
        {
            const f4* src = COEF + (size_t)tp * CF4_PER_TP;
#pragma unroll
            for (int k = 0; k < 6; ++k) {
                int i = k * BLOCK + threadIdx.x;
                if (i < CF4_PER_TP) CLs[i] = src[i];
            }
        }
        __syncthreads();

        const int* Ot = OFFS + tp * (36 * 12);

        p2 h2[6];
#pragma unroll
        for (int j3 = 0; j3 < 6; ++j3) {
            p2 h1[6];
#pragma unroll
            for (int j1 = 0; j1 < 6; ++j1) {
                const int* oi = Ot + (j3 * 6 + j1) * 12;
                p2 xs[6];
#pragma unroll
                for (int jj = 0; jj < 6; ++jj) {
                    int o0 = __builtin_amdgcn_readfirstlane(oi[2 * jj]);
                    int o1 = __builtin_amdgcn_readfirstlane(oi[2 * jj + 1]);
                    f2 va, vb;
                    va.x = *(const float*)(xc + o0 + voff0);
                    va.y = *(const float*)(xc + o1 + voff0);
                    vb.x = *(const float*)(xc + o0 + voff1);
                    vb.y = *(const float*)(xc + o1 + voff1);
                    xs[jj].a = va;
                    xs[jj].b = vb;
                }
                h1[j1] = contractD(&CLs[(j3 * 7 + j1) * 32], xs);
            }
            h2[j3] = contractD(&CLs[(j3 * 7 + 6) * 32], h1);
        }
        p2 r = contractD(&CLs[42 * 32], h2);

        size_t ob = ((size_t)b0 * COUT + 2 * tp) * NPOS + pos;
        out[ob]        = r.a.x;
        out[ob + NPOS] = r.a.y;
        size_t ob2 = ob + (size_t)BHALF * COUT * NPOS;
        out[ob2]        = r.b.x;
        out[ob2 + NPOS] = r.b.y;
    }
}

__global__ void prep_l(const int* __restrict__ map1, const float* __restrict__ lut1,
                       const int* __restrict__ map2, const float* __restrict__ lut2,
                       const int* __restrict__ map3, const float* __restrict__ lut3,
                       int* __restrict__ OFFS, float* __restrict__ COEF) {
    const int rec  = blockIdx.x % 43;
    const int tp   = blockIdx.x / 43;
    const int lane = threadIdx.x;
    const int t0 = 2 * tp, t1 = 2 * tp + 1;

    const float* lp0;
    const float* lp1;
    int node;
    if (rec == 42) {
        node = 42;
        lp0 = lut3 + t0 * 64;
        lp1 = lut3 + t1 * 64;
    } else {
        const int j3 = rec / 7;
        const int jr = rec - 7 * j3;
        const int n20 = map3[t0 * 6 + j3];
        const int n21 = map3[t1 * 6 + j3];
        if (jr == 6) {
            node = j3 * 7 + 6;
            lp0 = lut2 + (t0 * 6 + n20) * 64;
            lp1 = lut2 + (t1 * 6 + n21) * 64;
        } else {
            const int n10 = map2[(t0 * 6 + n20) * 6 + jr];
            const int n11 = map2[(t1 * 6 + n21) * 6 + jr];
            node = j3 * 7 + jr;
            lp0 = lut1 + (t0 * 36 + n10) * 64;
            lp1 = lut1 + (t1 * 36 + n11) * 64;
            if (lane < 12) {
                int h  = lane & 1;
                int jj = lane >> 1;
                int n1 = h ? n11 : n10;
                int t  = h ? t1 : t0;
                int m  = map1[(t * 36 + n1) * 6 + jj];
                int c  = m / 25;
                int r  = m - 25 * c;
                int kh = r / 5;
                int kw = r - 5 * kh;
                OFFS[(tp * 36 + j3 * 6 + jr) * 12 + jj * 2 + h] =
                    (c * HW_ + kh * W_ + kw) * 4;
            }
        }
    }

    float c0 = lp0[lane];
    float c1 = lp1[lane];
#pragma unroll
    for (int s = 1; s < 64; s <<= 1) {
        float o0 = __shfl_xor(c0, s);
        float o1 = __shfl_xor(c1, s);
        if (lane & s) { c0 -= o0; c1 -= o1; }
    }
    float* cp = COEF + ((size_t)tp * 43 + node) * 128;
    int slot = (lane >> 1) * 4 + (lane & 1) * 2;
    cp[slot]     = c0;
    cp[slot + 1] = c1;
}

// ---- Last-resort fallback: direct evaluation (no workspace needed) ----
__device__ __forceinline__ float clamp01(float v) {
    return __builtin_amdgcn_fmed3f(v, 0.0f, 1.0f);
}

__device__ __forceinline__ float contract64s(const float* __restrict__ L,
                                             const float xs[6]) {
    float v[32];
#pragma unroll
    for (int a = 0; a < 32; ++a) {
        float b = L[2 * a];
        v[a] = fmaf(xs[5], L[2 * a + 1] - b, b);
    }
#pragma unroll
    for (int a = 0; a < 16; ++a) v[a] = fmaf(xs[4], v[2*a+1] - v[2*a], v[2*a]);
#pragma unroll
    for (int a = 0; a < 8; ++a)  v[a] = fmaf(xs[3], v[2*a+1] - v[2*a], v[2*a]);
#pragma unroll
    for (int a = 0; a < 4; ++a)  v[a] = fmaf(xs[2], v[2*a+1] - v[2*a], v[2*a]);
#pragma unroll
    for (int a = 0; a < 2; ++a)  v[a] = fmaf(xs[1], v[2*a+1] - v[2*a], v[2*a]);
    return clamp01(fmaf(xs[0], v[1] - v[0], v[0]));
}

__global__ __launch_bounds__(BLOCK, 4)
void lutconv_fb(const float* __restrict__ x,
                const int* __restrict__ map1, const float* __restrict__ lut1,
                const int* __restrict__ map2, const float* __restrict__ lut2,
                const int* __restrict__ map3, const float* __restrict__ lut3,
                float* __restrict__ out) {
    const int g   = (blockIdx.x % 144) * BLOCK + threadIdx.x;
    const int tg  = blockIdx.x / 144;
    const int b   = g / NPOS;
    const int pos = g - b * NPOS;
    const int lin = (pos / OW_) * W_ + (pos - (pos / OW_) * OW_);
    const float* xb = x + (size_t)b * XSTRIDE;

#pragma unroll 1
    for (int tt = 0; tt < 8; ++tt) {
        const int t = tg * 8 + tt;
        float h2[6];
#pragma unroll
        for (int j3 = 0; j3 < 6; ++j3) {
            int n2 = __builtin_amdgcn_readfirstlane(map3[t * 6 + j3]);
            float h1[6];
#pragma unroll
            for (int j1 = 0; j1 < 6; ++j1) {
                int n1 = __builtin_amdgcn_readfirstlane(map2[(t * 6 + n2) * 6 + j1]);
                float xs[6];
#pragma unroll
                for (int jj = 0; jj < 6; ++jj) {
                    int m = map1[(t * 36 + n1) * 6 + jj];
                    int c = m / 25, r = m - 25 * c, kh = r / 5, kw = r - 5 * kh;
                    int off = __builtin_amdgcn_readfirstlane(c * HW_ + kh * W_ + kw);
                    xs[jj] = xb[off + lin];
                }
                h1[j1] = contract64s(lut1 + (t * 36 + n1) * 64, xs);
            }
            h2[j3] = contract64s(lut2 + (t * 6 + n2) * 64, h1);
        }
        out[((size_t)b * COUT + t) * NPOS + pos] = contract64s(lut3 + t * 64, h2);
    }
}

extern "C" void kernel_launch(void* const* d_in, const int* in_sizes, int n_in,
                              void* d_out, int out_size, void* d_ws, size_t ws_size,
                              hipStream_t stream) {
    const float* x    = (const float*)d_in[0];
    const int*   map1 = (const int*)d_in[1];
    const float* lut1 = (const float*)d_in[2];
    const int*   map2 = (const int*)d_in[3];
    const float* lut2 = (const float*)d_in[4];
    const int*   map3 = (const int*)d_in[5];
    const float* lut3 = (const float*)d_in[6];
    float* out = (float*)d_out;

    if (ws_size >= (size_t)WS_NEW) {
        f2*    xp   = (f2*)d_ws;
        int*   OFFS = (int*)((char*)d_ws + XP_BYTES);
        float* COEF = (float*)((char*)d_ws + XP_BYTES + OFF_BYTES);

        prep_xp<<<(32 * PSTRIDE + 255) / 256, 256, 0, stream>>>(x, xp);
        prep_cf2<<<COUT * 43, 64, 0, stream>>>(map1, lut1, map2, lut2, map3, lut3,
                                               OFFS, COEF);
        lutconv_s<<<NCH * COUT, BLK, 0, stream>>>((const char*)xp, OFFS,
                                                  (const f4*)COEF, out);
    } else if (ws_size >= (size_t)WS_R6) {
        int*   OFFS = (int*)d_ws;
        float* COEF = (float*)((char*)d_ws + OFF6_INTS * 4);
        prep_l<<<NTP * 43, 64, 0, stream>>>(map1, lut1, map2, lut2, map3, lut3,
                                            OFFS, COEF);
        lutconv_l<<<UBLOCKS6 * TGROUPS6, BLOCK, 0, stream>>>(
            x, OFFS, (const f4*)COEF, out);
    } else {
        lutconv_fb<<<144 * 16, BLOCK, 0, stream>>>(
            x, map1, lut1, map2, lut2, map3, lut3, out);
    }
}

// Round 10
// 436.127 us; speedup vs baseline: 1.0674x; 1.0674x over previous
//
#include <hip/hip_runtime.h>

// Problem constants
#define B_      64
#define CIN     32
#define H_      28
#define W_      28
#define OH_     24
#define OW_     24
#define COUT    128
#define NPOS    (OH_ * OW_)          // 576
#define HW_     (H_ * W_)            // 784
#define XSTRIDE (CIN * HW_)          // 25088 floats per image
#define PSTRIDE (CIN * HW_)          // f2 elements per image-pair block

// ---------------- Main path: 4 images/lane, 1 tree/block, FULL UNROLL ----------------
#define BLK      192
#define NQ       16                  // bq in [0,16): images bq,+16,+32,+48
#define NLANES   (NQ * NPOS)         // 9216
#define NCH      (NLANES / BLK)      // 48 chunks
#define NXCD     8
#define CPX      (NCH / NXCD)        // 6 chunks per XCD
// grid = NCH * COUT = 6144

// WS: XPAIR f2[32*PSTRIDE] | OFFS int[COUT*36*6] | COEF2 f4[COUT*43*32] (dup records)
#define XP_BYTES    (32 * PSTRIDE * 8)          // 6422528
#define OFF_BYTES   (COUT * 36 * 6 * 4)         // 110592
#define COEF2_BYTES (COUT * 43 * 32 * 16)       // 2818048
#define WS_NEW      (XP_BYTES + OFF_BYTES + COEF2_BYTES)   // ~9.35 MB

// ---------------- r6 fallback path constants (proven 374 us) ----------------
#define BLOCK    256
#define BHALF    32
#define NLANES6  (BHALF * NPOS)      // 18432
#define UBLOCKS6 (NLANES6 / BLOCK)   // 72
#define TPB6     2
#define NTP      64
#define TGROUPS6 (NTP / TPB6)        // 32
#define UPX6     (UBLOCKS6 / NXCD)   // 9
#define CF4_PER_TP (43 * 32)
#define OFF6_INTS  (NTP * 36 * 12)
#define WS_R6      ((OFF6_INTS + NTP * 43 * 128) * 4)    // 1519616

typedef float f2 __attribute__((ext_vector_type(2)));
typedef float f4 __attribute__((ext_vector_type(4)));
struct p2 { f2 a, b; };   // two image-pair units per lane

__device__ __forceinline__ f2 pkfma(f2 x, f2 h, f2 l) {
    return __builtin_elementwise_fma(x, h, l);   // v_pk_fma_f32 (no asm: r5 lesson)
}

__device__ __forceinline__ f2 clamp2(f2 v) {
    f2 r;
    r.x = __builtin_amdgcn_fmed3f(v.x, 0.0f, 1.0f);
    r.y = __builtin_amdgcn_fmed3f(v.y, 0.0f, 1.0f);
    return r;
}

// DFS Horner contraction. Record a0 is an f4 whose {x,y} and {z,w} are the
// ALIGNED sub-pairs the leaf pkfma consumes directly (mov-free; r7's splat
// variant cost ~128 v_movs/node). Layouts:
//   main path: {lo,lo,hi,hi} (f2 lanes = image pair)
//   r6 path:   {lo_t0,lo_t1,hi_t0,hi_t1} (f2 lanes = tree pair)
template<int M>
struct RecD {
    static __device__ __forceinline__ p2 go(const f4* __restrict__ C, int a0,
                                            const p2* xs) {
        p2 lo = RecD<M - 1>::go(C, a0, xs);
        p2 hi = RecD<M - 1>::go(C, a0 + (1 << (M - 2)), xs);
        p2 r;
        r.a = pkfma(xs[6 - M].a, hi.a, lo.a);
        r.b = pkfma(xs[6 - M].b, hi.b, lo.b);
        return r;
    }
};
template<>
struct RecD<1> {
    static __device__ __forceinline__ p2 go(const f4* __restrict__ C, int a0,
                                            const p2* xs) {
        f4 q = C[a0];                 // ds_read_b128, uniform addr -> broadcast
        f2 lo; lo.x = q.x; lo.y = q.y;
        f2 hi; hi.x = q.z; hi.y = q.w;
        p2 r;
        r.a = pkfma(xs[5].a, hi, lo);
        r.b = pkfma(xs[5].b, hi, lo);
        return r;
    }
};

__device__ __forceinline__ p2 contractD(const f4* __restrict__ C, const p2 xs[6]) {
    p2 r = RecD<6>::go(C, 0, xs);
    r.a = clamp2(r.a);
    r.b = clamp2(r.b);
    return r;
}

// Main kernel: one tree per block, FULLY UNROLLED tree body (r9 proved rolling
// hurts: cross-node ILP is what hides gather latency). 22KB LDS + VGPR<=64
// (launch_bounds(192,8)) -> 7 blocks/CU = 21 waves (vs r6/r9's ~12).
__global__ __launch_bounds__(BLK, 8)
void lutconv_u(const char* __restrict__ xpc,
               const int* __restrict__ OFFS,
               const f4* __restrict__ COEF,
               float* __restrict__ out) {
    __shared__ f4 CLs[43 * 32];          // 22016 B coeff image (duplicated records)

    // XCD-locality decode (r9-proven: FETCH 19.8MB): 6 chunks pinned per XCD.
    const int bid = blockIdx.x;
    const int xcd = bid & 7;
    const int j   = bid >> 3;            // 0..767
    const int t   = j & 127;             // tree
    const int usl = j >> 7;              // 0..5
    const int us  = xcd * CPX + usl;     // chunk 0..47

    // Stage coefficients: 1376 f4.
    {
        const f4* src = COEF + (size_t)t * (43 * 32);
#pragma unroll
        for (int k = 0; k < 8; ++k) {
            int i = k * BLK + threadIdx.x;
            if (i < 43 * 32) CLs[i] = src[i];
        }
    }

    const int g   = us * BLK + threadIdx.x;    // 0..9215
    const int bq  = g / NPOS;                  // 0..15
    const int pos = g - bq * NPOS;
    const int oh  = pos / OW_;
    const int ow  = pos - oh * OW_;
    const unsigned lin   = oh * W_ + ow;
    const unsigned byteA = (bq * PSTRIDE + lin) * 8u;          // pair (bq, bq+32)
    const unsigned byteB = ((bq + 16) * PSTRIDE + lin) * 8u;   // pair (bq+16, bq+48)
    const int* Ot = OFFS + t * 216;
    __syncthreads();

    p2 h2[6];
#pragma unroll
    for (int j3 = 0; j3 < 6; ++j3) {
        p2 h1[6];
#pragma unroll
        for (int j1 = 0; j1 < 6; ++j1) {
            p2 xs[6];
#pragma unroll
            for (int jj = 0; jj < 6; ++jj) {
                int o = __builtin_amdgcn_readfirstlane(Ot[(j3 * 6 + j1) * 6 + jj]);
                const char* p = xpc + o;             // scalar base
                p2 w;
                w.a = *(const f2*)(p + byteA);       // global_load_dwordx2 saddr
                w.b = *(const f2*)(p + byteB);
                xs[jj] = w;
            }
            h1[j1] = contractD(CLs + (j3 * 7 + j1) * 32, xs);
        }
        h2[j3] = contractD(CLs + (j3 * 7 + 6) * 32, h1);
    }
    p2 r = contractD(CLs + 42 * 32, h2);

    const size_t istr = (size_t)16 * COUT * NPOS;
    size_t o0 = ((size_t)bq * COUT + t) * NPOS + pos;
    out[o0]            = r.a.x;   // bq
    out[o0 + 2 * istr] = r.a.y;   // bq+32
    out[o0 + istr]     = r.b.x;   // bq+16
    out[o0 + 3 * istr] = r.b.y;   // bq+48
}

// Interleave image pairs (p, p+32) as f2.
__global__ void prep_xp(const float* __restrict__ x, f2* __restrict__ xp) {
    int i = blockIdx.x * 256 + threadIdx.x;
    if (i < 32 * PSTRIDE) {
        int p = i / PSTRIDE;
        int r = i - p * PSTRIDE;
        f2 v;
        v.x = x[p * XSTRIDE + r];
        v.y = x[(p + 32) * XSTRIDE + r];
        xp[i] = v;
    }
}

// Per (tree, node): resolve maps, Mobius-transform LUT (shfl_xor butterfly),
// write DUPLICATED records {lo,lo,hi,hi} + byte gather offsets (x8 for f2).
__global__ void prep_cf2(const int* __restrict__ map1, const float* __restrict__ lut1,
                         const int* __restrict__ map2, const float* __restrict__ lut2,
                         const int* __restrict__ map3, const float* __restrict__ lut3,
                         int* __restrict__ OFFS, float* __restrict__ COEF) {
    const int rec  = blockIdx.x % 43;
    const int t    = blockIdx.x / 43;
    const int lane = threadIdx.x;

    const float* lp;
    int node;
    if (rec == 42) {
        node = 42;
        lp = lut3 + t * 64;
    } else {
        const int j3 = rec / 7;
        const int jr = rec - 7 * j3;
        const int n2 = map3[t * 6 + j3];
        if (jr == 6) {
            node = j3 * 7 + 6;
            lp = lut2 + (t * 6 + n2) * 64;
        } else {
            const int n1 = map2[(t * 6 + n2) * 6 + jr];
            node = j3 * 7 + jr;
            lp = lut1 + (t * 36 + n1) * 64;
            if (lane < 6) {
                int m  = map1[(t * 36 + n1) * 6 + lane];
                int c  = m / 25;
                int r  = m - 25 * c;
                int kh = r / 5;
                int kw = r - 5 * kh;
                OFFS[t * 216 + (j3 * 6 + jr) * 6 + lane] =
                    (c * HW_ + kh * W_ + kw) * 8;   // byte offset into f2 block
            }
        }
    }

    float cv = lp[lane];
#pragma unroll
    for (int s = 1; s < 64; s <<= 1) {
        float o = __shfl_xor(cv, s);
        if (lane & s) cv -= o;
    }
    // Duplicated record: entry-pair a={lane>>1}, half h={lane&1} (0=lo,1=hi):
    // f4 = {lo,lo,hi,hi}.
    float* cp = COEF + ((size_t)t * 43 + node) * 128;
    int a = lane >> 1, h = lane & 1;
    cp[a * 4 + h * 2]     = cv;
    cp[a * 4 + h * 2 + 1] = cv;
}

// ======================= r6 fallback path (proven 374 us) =======================
__global__ __launch_bounds__(BLOCK, 3)
void lutconv_l(const float* __restrict__ x,
               const int* __restrict__ OFFS,
               const f4* __restrict__ COEF,
               float* __restrict__ out) {
    __shared__ f4 CLs[CF4_PER_TP];

    const int bid = blockIdx.x;
    const int xcd = bid % NXCD;
    const int j   = bid / NXCD;
    const int tg  = j % TGROUPS6;
    const int us  = j / TGROUPS6;
    const int u   = xcd * UPX6 + us;

    const int g   = u * BLOCK + threadIdx.x;
    const int b0  = g / NPOS;
    const int pos = g - b0 * NPOS;
    const int oh  = pos / OW_;
    const int ow  = pos - oh * OW_;
    const unsigned lin   = oh * W_ + ow;
    const unsigned voff0 = (b0 * XSTRIDE + lin) * 4u;
    const unsigned voff1 = voff0 + BHALF * XSTRIDE * 4u;
    const char* xc = (const char*)x;

#pragma unroll 1
    for (int tpi = 0; tpi < TPB6; ++tpi) {
        const int tp = tg * TPB6 + tpi;

        if (tpi) __syncthreads();
        {
            const f4* src = COEF + (size_t)tp * CF4_PER_TP;
#pragma unroll
            for (int k = 0; k < 6; ++k) {
                int i = k * BLOCK + threadIdx.x;
                if (i < CF4_PER_TP) CLs[i] = src[i];
            }
        }
        __syncthreads();

        const int* Ot = OFFS + tp * (36 * 12);

        p2 h2[6];
#pragma unroll
        for (int j3 = 0; j3 < 6; ++j3) {
            p2 h1[6];
#pragma unroll
            for (int j1 = 0; j1 < 6; ++j1) {
                const int* oi = Ot + (j3 * 6 + j1) * 12;
                p2 xs[6];
#pragma unroll
                for (int jj = 0; jj < 6; ++jj) {
                    int o0 = __builtin_amdgcn_readfirstlane(oi[2 * jj]);
                    int o1 = __builtin_amdgcn_readfirstlane(oi[2 * jj + 1]);
                    f2 va, vb;
                    va.x = *(const float*)(xc + o0 + voff0);
                    va.y = *(const float*)(xc + o1 + voff0);
                    vb.x = *(const float*)(xc + o0 + voff1);
                    vb.y = *(const float*)(xc + o1 + voff1);
                    xs[jj].a = va;
                    xs[jj].b = vb;
                }
                h1[j1] = contractD(&CLs[(j3 * 7 + j1) * 32], xs);
            }
            h2[j3] = contractD(&CLs[(j3 * 7 + 6) * 32], h1);
        }
        p2 r = contractD(&CLs[42 * 32], h2);

        size_t ob = ((size_t)b0 * COUT + 2 * tp) * NPOS + pos;
        out[ob]        = r.a.x;
        out[ob + NPOS] = r.a.y;
        size_t ob2 = ob + (size_t)BHALF * COUT * NPOS;
        out[ob2]        = r.b.x;
        out[ob2 + NPOS] = r.b.y;
    }
}

__global__ void prep_l(const int* __restrict__ map1, const float* __restrict__ lut1,
                       const int* __restrict__ map2, const float* __restrict__ lut2,
                       const int* __restrict__ map3, const float* __restrict__ lut3,
                       int* __restrict__ OFFS, float* __restrict__ COEF) {
    const int rec  = blockIdx.x % 43;
    const int tp   = blockIdx.x / 43;
    const int lane = threadIdx.x;
    const int t0 = 2 * tp, t1 = 2 * tp + 1;

    const float* lp0;
    const float* lp1;
    int node;
    if (rec == 42) {
        node = 42;
        lp0 = lut3 + t0 * 64;
        lp1 = lut3 + t1 * 64;
    } else {
        const int j3 = rec / 7;
        const int jr = rec - 7 * j3;
        const int n20 = map3[t0 * 6 + j3];
        const int n21 = map3[t1 * 6 + j3];
        if (jr == 6) {
            node = j3 * 7 + 6;
            lp0 = lut2 + (t0 * 6 + n20) * 64;
            lp1 = lut2 + (t1 * 6 + n21) * 64;
        } else {
            const int n10 = map2[(t0 * 6 + n20) * 6 + jr];
            const int n11 = map2[(t1 * 6 + n21) * 6 + jr];
            node = j3 * 7 + jr;
            lp0 = lut1 + (t0 * 36 + n10) * 64;
            lp1 = lut1 + (t1 * 36 + n11) * 64;
            if (lane < 12) {
                int h  = lane & 1;
                int jj = lane >> 1;
                int n1 = h ? n11 : n10;
                int t  = h ? t1 : t0;
                int m  = map1[(t * 36 + n1) * 6 + jj];
                int c  = m / 25;
                int r  = m - 25 * c;
                int kh = r / 5;
                int kw = r - 5 * kh;
                OFFS[(tp * 36 + j3 * 6 + jr) * 12 + jj * 2 + h] =
                    (c * HW_ + kh * W_ + kw) * 4;
            }
        }
    }

    float c0 = lp0[lane];
    float c1 = lp1[lane];
#pragma unroll
    for (int s = 1; s < 64; s <<= 1) {
        float o0 = __shfl_xor(c0, s);
        float o1 = __shfl_xor(c1, s);
        if (lane & s) { c0 -= o0; c1 -= o1; }
    }
    float* cp = COEF + ((size_t)tp * 43 + node) * 128;
    int slot = (lane >> 1) * 4 + (lane & 1) * 2;
    cp[slot]     = c0;
    cp[slot + 1] = c1;
}

// ---- Last-resort fallback: direct evaluation (no workspace needed) ----
__device__ __forceinline__ float clamp01(float v) {
    return __builtin_amdgcn_fmed3f(v, 0.0f, 1.0f);
}

__device__ __forceinline__ float contract64s(const float* __restrict__ L,
                                             const float xs[6]) {
    float v[32];
#pragma unroll
    for (int a = 0; a < 32; ++a) {
        float b = L[2 * a];
        v[a] = fmaf(xs[5], L[2 * a + 1] - b, b);
    }
#pragma unroll
    for (int a = 0; a < 16; ++a) v[a] = fmaf(xs[4], v[2*a+1] - v[2*a], v[2*a]);
#pragma unroll
    for (int a = 0; a < 8; ++a)  v[a] = fmaf(xs[3], v[2*a+1] - v[2*a], v[2*a]);
#pragma unroll
    for (int a = 0; a < 4; ++a)  v[a] = fmaf(xs[2], v[2*a+1] - v[2*a], v[2*a]);
#pragma unroll
    for (int a = 0; a < 2; ++a)  v[a] = fmaf(xs[1], v[2*a+1] - v[2*a], v[2*a]);
    return clamp01(fmaf(xs[0], v[1] - v[0], v[0]));
}

__global__ __launch_bounds__(BLOCK, 4)
void lutconv_fb(const float* __restrict__ x,
                const int* __restrict__ map1, const float* __restrict__ lut1,
                const int* __restrict__ map2, const float* __restrict__ lut2,
                const int* __restrict__ map3, const float* __restrict__ lut3,
                float* __restrict__ out) {
    const int g   = (blockIdx.x % 144) * BLOCK + threadIdx.x;
    const int tg  = blockIdx.x / 144;
    const int b   = g / NPOS;
    const int pos = g - b * NPOS;
    const int lin = (pos / OW_) * W_ + (pos - (pos / OW_) * OW_);
    const float* xb = x + (size_t)b * XSTRIDE;

#pragma unroll 1
    for (int tt = 0; tt < 8; ++tt) {
        const int t = tg * 8 + tt;
        float h2[6];
#pragma unroll
        for (int j3 = 0; j3 < 6; ++j3) {
            int n2 = __builtin_amdgcn_readfirstlane(map3[t * 6 + j3]);
            float h1[6];
#pragma unroll
            for (int j1 = 0; j1 < 6; ++j1) {
                int n1 = __builtin_amdgcn_readfirstlane(map2[(t * 6 + n2) * 6 + j1]);
                float xs[6];
#pragma unroll
                for (int jj = 0; jj < 6; ++jj) {
                    int m = map1[(t * 36 + n1) * 6 + jj];
                    int c = m / 25, r = m - 25 * c, kh = r / 5, kw = r - 5 * kh;
                    int off = __builtin_amdgcn_readfirstlane(c * HW_ + kh * W_ + kw);
                    xs[jj] = xb[off + lin];
                }
                h1[j1] = contract64s(lut1 + (t * 36 + n1) * 64, xs);
            }
            h2[j3] = contract64s(lut2 + (t * 6 + n2) * 64, h1);
        }
        out[((size_t)b * COUT + t) * NPOS + pos] = contract64s(lut3 + t * 64, h2);
    }
}

extern "C" void kernel_launch(void* const* d_in, const int* in_sizes, int n_in,
                              void* d_out, int out_size, void* d_ws, size_t ws_size,
                              hipStream_t stream) {
    const float* x    = (const float*)d_in[0];
    const int*   map1 = (const int*)d_in[1];
    const float* lut1 = (const float*)d_in[2];
    const int*   map2 = (const int*)d_in[3];
    const float* lut2 = (const float*)d_in[4];
    const int*   map3 = (const int*)d_in[5];
    const float* lut3 = (const float*)d_in[6];
    float* out = (float*)d_out;

    if (ws_size >= (size_t)WS_NEW) {
        f2*    xp   = (f2*)d_ws;
        int*   OFFS = (int*)((char*)d_ws + XP_BYTES);
        float* COEF = (float*)((char*)d_ws + XP_BYTES + OFF_BYTES);

        prep_xp<<<(32 * PSTRIDE + 255) / 256, 256, 0, stream>>>(x, xp);
        prep_cf2<<<COUT * 43, 64, 0, stream>>>(map1, lut1, map2, lut2, map3, lut3,
                                               OFFS, COEF);
        lutconv_u<<<NCH * COUT, BLK, 0, stream>>>((const char*)xp, OFFS,
                                                  (const f4*)COEF, out);
    } else if (ws_size >= (size_t)WS_R6) {
        int*   OFFS = (int*)d_ws;
        float* COEF = (float*)((char*)d_ws + OFF6_INTS * 4);
        prep_l<<<NTP * 43, 64, 0, stream>>>(map1, lut1, map2, lut2, map3, lut3,
                                            OFFS, COEF);
        lutconv_l<<<UBLOCKS6 * TGROUPS6, BLOCK, 0, stream>>>(
            x, OFFS, (const f4*)COEF, out);
    } else {
        lutconv_fb<<<144 * 16, BLOCK, 0, stream>>>(
            x, map1, lut1, map2, lut2, map3, lut3, out);
    }
}